// Round 1
// 210.338 us; speedup vs baseline: 1.0418x; 1.0418x over previous
//
#include <hip/hip_runtime.h>
#include <math.h>

#define BB   2
#define NCAM 6
#define CH   256
#define COUT 128
#define HF   32
#define WF   88
#define NPIX (BB * NCAM * HF * WF)   // 33792
#define NV   100000
#define CIN  128
#define VPB  40                      // voxels per block in voxel_gather

typedef __attribute__((ext_vector_type(8))) short short8;
typedef __attribute__((ext_vector_type(4))) float f32x4;

static __device__ inline short f2bf(float f) {
    union { float f; unsigned u; } v; v.f = f;
    unsigned r = (v.u + 0x7fffu + ((v.u >> 16) & 1u)) >> 16;  // RNE
    return (short)r;
}
static __device__ inline float bflo(unsigned int pk) {
    union { unsigned int u; float f; } a; a.u = pk << 16; return a.f;
}
static __device__ inline float bfhi(unsigned int pk) {
    union { unsigned int u; float f; } a; a.u = pk & 0xffff0000u; return a.f;
}

// blockIdx 0: params (24 doubles per (b,cam): M[9], v[3], Rpost[9], tpost[3])
// blockIdx 1..64: W[o][c] (128x256 fp32) -> fragment-linear bf16 B-operand
__global__ void prep_params_w(const float* __restrict__ intrins,
                              const float* __restrict__ post_rots,
                              const float* __restrict__ post_trans,
                              const float* __restrict__ bda,
                              const float* __restrict__ l2c,
                              const float* __restrict__ W,
                              double* __restrict__ params,
                              short*  __restrict__ Wbf)
{
    if (blockIdx.x > 0) {
        int chunk = blockIdx.x - 1;      // nt*8+kk, 64 chunks
        int l = threadIdx.x;             // 64 lanes
        int nt = chunk >> 3, kk = chunk & 7;
        int n = nt * 16 + (l & 15);
        int k = kk * 32 + (l >> 4) * 8;
        short v[8];
        #pragma unroll
        for (int j = 0; j < 8; j++) v[j] = f2bf(W[n * CH + k + j]);
        *(short8*)(Wbf + ((size_t)chunk * 64 + l) * 8) = *(short8*)v;
        return;
    }

    int t = threadIdx.x;
    if (t >= BB * NCAM) return;
    int b = t / NCAM;

    const float* Bm = bda + b * 16;
    double a00 = Bm[0], a01 = Bm[1], a02 = Bm[2],  tx = Bm[3];
    double a10 = Bm[4], a11 = Bm[5], a12 = Bm[6],  ty = Bm[7];
    double a20 = Bm[8], a21 = Bm[9], a22 = Bm[10], tz = Bm[11];

    double det = a00*(a11*a22 - a12*a21) - a01*(a10*a22 - a12*a20) + a02*(a10*a21 - a11*a20);
    double id  = 1.0 / det;
    double inv[3][3];
    inv[0][0] =  (a11*a22 - a12*a21) * id;
    inv[0][1] = -(a01*a22 - a02*a21) * id;
    inv[0][2] =  (a01*a12 - a02*a11) * id;
    inv[1][0] = -(a10*a22 - a12*a20) * id;
    inv[1][1] =  (a00*a22 - a02*a20) * id;
    inv[1][2] = -(a00*a12 - a02*a10) * id;
    inv[2][0] =  (a10*a21 - a11*a20) * id;
    inv[2][1] = -(a00*a21 - a01*a20) * id;
    inv[2][2] =  (a00*a11 - a01*a10) * id;

    const float* In = intrins + t * 9;
    const float* Lc = l2c + t * 16;

    double M3[3][3];
    #pragma unroll
    for (int i = 0; i < 3; i++)
        #pragma unroll
        for (int j = 0; j < 3; j++)
            M3[i][j] = (double)In[i*3+0] * (double)Lc[j*4+0]
                     + (double)In[i*3+1] * (double)Lc[j*4+1]
                     + (double)In[i*3+2] * (double)Lc[j*4+2];

    double M[3][3];
    #pragma unroll
    for (int i = 0; i < 3; i++)
        #pragma unroll
        for (int j = 0; j < 3; j++)
            M[i][j] = M3[i][0]*inv[0][j] + M3[i][1]*inv[1][j] + M3[i][2]*inv[2][j];

    double* P = params + t * 24;
    #pragma unroll
    for (int i = 0; i < 3; i++)
        #pragma unroll
        for (int j = 0; j < 3; j++)
            P[i*3+j] = M[i][j];
    #pragma unroll
    for (int i = 0; i < 3; i++)
        P[9+i] = -(M[i][0]*tx + M[i][1]*ty + M[i][2]*tz);
    #pragma unroll
    for (int i = 0; i < 9; i++) P[12+i] = (double)post_rots[t*9 + i];
    #pragma unroll
    for (int i = 0; i < 3; i++) P[21+i] = (double)post_trans[t*3 + i];
}

// imgP[pix][out] = bf16( img[bc][:,pix] @ W^T )  — one GEMM per unique pixel.
// wave = 16 pixels x 128 outs, K=256. A read straight from img fp32 (64B segments),
// B from fragment-linear Wbf (L2-resident). No LDS, no barriers.
__global__ __launch_bounds__(256) void pixel_mm(const float* __restrict__ img,
                                                const short* __restrict__ Wbf,
                                                unsigned short* __restrict__ imgP)
{
    const int w    = (blockIdx.x << 2) + (threadIdx.x >> 6);   // 0..2111
    const int lane = threadIdx.x & 63;
    const int bc   = w / 176;                                  // 2816/16 tiles per (b,cam)
    const int pt   = w - bc * 176;
    const int pix0 = pt * 16;

    const float* A0 = img + (size_t)bc * (CH * HF * WF) + pix0 + (lane & 15);
    const int q8 = (lane >> 4) * 8;

    f32x4 acc[8];
    #pragma unroll
    for (int nt = 0; nt < 8; nt++) acc[nt] = (f32x4){0.f, 0.f, 0.f, 0.f};

    const short8* Bf = (const short8*)Wbf;
    for (int kk = 0; kk < 8; kk++) {
        short av[8];
        #pragma unroll
        for (int j = 0; j < 8; j++)
            av[j] = f2bf(A0[(size_t)(kk * 32 + q8 + j) * (HF * WF)]);
        short8 a = *(short8*)av;
        #pragma unroll
        for (int nt = 0; nt < 8; nt++)
            acc[nt] = __builtin_amdgcn_mfma_f32_16x16x32_bf16(
                          a, Bf[(nt * 8 + kk) * 64 + lane], acc[nt], 0, 0, 0);
    }

    // C/D: col = lane&15 (out within tile), row = (lane>>4)*4 + r (pixel)
    const int col = lane & 15, rq = lane >> 4;
    unsigned short* P0 = imgP + ((size_t)bc * (HF * WF) + pix0 + rq * 4) * COUT + col;
    #pragma unroll
    for (int nt = 0; nt < 8; nt++)
        #pragma unroll
        for (int r = 0; r < 4; r++)
            P0[(size_t)r * COUT + nt * 16] = (unsigned short)f2bf(acc[nt][r]);
}

struct POF { int o; float m; };

// Per block: copy VPB voxel passthrough rows + coords, fp64-project VPB*6 pairs,
// then per voxel sum the valid cams' imgP rows (coalesced 256B each) and write fp32.
__global__ __launch_bounds__(256) void voxel_gather(
    const float*          __restrict__ vf,
    const int*            __restrict__ coords,
    const unsigned short* __restrict__ imgP,
    const double*         __restrict__ params,
    float*                __restrict__ out)
{
    const int t  = threadIdx.x;
    const int n0 = blockIdx.x * VPB;

    // ---- passthrough copy: 40 vox x 128 ch = 1280 float4 ----
    {
        const float4* vf4 = (const float4*)vf;
        float4*       o4  = (float4*)out;
        int base = n0 * (CIN / 4);
        #pragma unroll
        for (int i = 0; i < 5; i++)
            o4[base + i * 256 + t] = vf4[base + i * 256 + t];
    }
    if (t < VPB * 4) {
        int gi = n0 * 4 + t;
        float cv = (float)coords[gi];
        const size_t cb = (size_t)2 * NV * CIN;
        out[cb + gi]                  = cv;
        out[cb + (size_t)NV * 4 + gi] = cv;
    }

    __shared__ POF pof[VPB][NCAM];   // 1.9 KB

    // ---- fp64 projection: one thread per (voxel, cam), 240 pairs ----
    if (t < VPB * NCAM) {
        int vi = t / NCAM, c = t - vi * NCAM;
        int n  = n0 + vi;
        int b  = coords[n * 4 + 0];
        int zi = coords[n * 4 + 1];
        int yi = coords[n * 4 + 2];
        int xi = coords[n * 4 + 3];
        double px = (double)xi * (double)0.075f + (-54.0);
        double py = (double)yi * (double)0.075f + (-54.0);
        double pz = (double)zi * (double)0.2f   + (-5.0);
        const double* P = params + (b * NCAM + c) * 24;
        double X = P[0]*px + P[1]*py + P[2]*pz + P[9];
        double Y = P[3]*px + P[4]*py + P[5]*pz + P[10];
        double Z = P[6]*px + P[7]*py + P[8]*pz + P[11];
        double u = X / Z;
        double v = Y / Z;
        double q0 = P[12]*u + P[13]*v + P[14]*Z + P[21];
        double q1 = P[15]*u + P[16]*v + P[17]*Z + P[22];
        double q2 = P[18]*u + P[19]*v + P[20]*Z + P[23];
        double cx = rint(q0 * 0.125);
        double cy = rint(q1 * 0.125);
        bool m = (cx >= 0.0) && (cx < (double)WF) && (cy >= 0.0) && (cy < (double)HF)
              && (q2 < 60.0) && (q2 >= 1.0);
        int o = 0;
        if (m) {
            int ix = (int)cx, iy = (int)cy;
            o = ((b * NCAM + c) * HF + iy) * WF + ix;   // global pixel index
        }
        POF p2; p2.o = o; p2.m = m ? 1.0f : 0.0f;
        pof[vi][c] = p2;
    }
    __syncthreads();

    // ---- masked cam-sum of precomputed imgP rows ----
    // half-wave (32 lanes) per voxel: each lane owns 4 out-channels (uint2 = 4 bf16).
    // Masked cams branch off per half-wave -> no loads issued for invalid cams.
    const int h = t >> 5, l32 = t & 31;
    #pragma unroll
    for (int vv = 0; vv < 5; vv++) {
        int vi = h * 5 + vv;
        float a0 = 0.f, a1 = 0.f, a2 = 0.f, a3 = 0.f;
        #pragma unroll
        for (int c = 0; c < NCAM; c++) {
            POF p2 = pof[vi][c];                      // LDS broadcast across half-wave
            if (p2.m != 0.0f) {
                const unsigned short* px = imgP + (size_t)p2.o * COUT + l32 * 4;
                uint2 A = *(const uint2*)px;          // coalesced 256B per voxel
                a0 += bflo(A.x); a1 += bfhi(A.x);
                a2 += bflo(A.y); a3 += bfhi(A.y);
            }
        }
        float4 r4 = {a0, a1, a2, a3};
        *(float4*)(out + ((size_t)NV + n0 + vi) * CIN + l32 * 4) = r4;
    }
}

extern "C" void kernel_launch(void* const* d_in, const int* in_sizes, int n_in,
                              void* d_out, int out_size, void* d_ws, size_t ws_size,
                              hipStream_t stream)
{
    const float* vf      = (const float*)d_in[0];
    const int*   coords  = (const int*)d_in[1];
    const float* img     = (const float*)d_in[2];
    const float* intrins = (const float*)d_in[3];
    const float* prots   = (const float*)d_in[4];
    const float* ptrans  = (const float*)d_in[5];
    const float* bda     = (const float*)d_in[6];
    const float* l2c     = (const float*)d_in[7];
    const float* W       = (const float*)d_in[8];
    float* out = (float*)d_out;

    double* params = (double*)d_ws;
    const size_t wbf_off  = 4096;
    const size_t wbf_sz   = (size_t)8 * 8 * 64 * 8 * sizeof(short);   // 64 KB
    const size_t imgP_off = wbf_off + wbf_sz;                         // 69632

    short*          Wbf  = (short*)((char*)d_ws + wbf_off);
    unsigned short* imgP = (unsigned short*)((char*)d_ws + imgP_off); // 8.65 MB

    prep_params_w<<<65, 64, 0, stream>>>(intrins, prots, ptrans, bda, l2c, W, params, Wbf);
    pixel_mm<<<(12 * 176) / 4, 256, 0, stream>>>(img, Wbf, imgP);
    voxel_gather<<<NV / VPB, 256, 0, stream>>>(vf, coords, imgP, params, out);
}